// Round 4
// baseline (3630.685 us; speedup 1.0000x reference)
//
#include <hip/hip_runtime.h>

#define NUu 500000
#define NIi 100000
#define FDIM 300
#define DDIM 64
#define NEe 2000000
#define ELl 1000000

// bucket config: 128 destination nodes per bucket (both sides)
#define BSZL 7
#define BSZ 128
#define NB_I 782      // ceil(NIi/128)
#define NB_U 3907     // ceil(NUu/128)
#define NBT (NB_I + NB_U)   // 4689
#define SH_I 19       // scat_i: src user (19 bits) | d_local << 19
#define SH_U 17       // scat_u: dst item (17 bits) | s_local << 17
#define ASTRIDE 65    // LDS accum row stride in floats (bank spread)

typedef __attribute__((ext_vector_type(8))) short s8v;
typedef __attribute__((ext_vector_type(4))) short s4v;
typedef __attribute__((ext_vector_type(4))) float f4v;
typedef unsigned short u16;

__device__ __forceinline__ float bf2f(u16 h) {
    union { unsigned u; float f; } x; x.u = ((unsigned)h) << 16; return x.f;
}
__device__ __forceinline__ u16 f2bf(float f) {
    union { float f; unsigned u; } x; x.f = f;
    unsigned u = x.u;
    u += 0x7FFFu + ((u >> 16) & 1u);   // round-to-nearest-even
    return (u16)(u >> 16);
}

// ---------------- cast user embeddings (with user_node_id gather) to bf16 ----
__global__ __launch_bounds__(256) void k_cast_users(const float* __restrict__ ue,
                                                    const int* __restrict__ uid,
                                                    u16* __restrict__ xu) {
    int idx = blockIdx.x * 256 + threadIdx.x;   // one thread = 4 elems
    int n  = idx >> 4;
    int d0 = (idx & 15) * 4;
    int src = uid[n];
    const float4* p = (const float4*)(ue + (size_t)src * DDIM + d0);
    float4 v = *p;
    s4v o;
    o[0] = (short)f2bf(v.x); o[1] = (short)f2bf(v.y);
    o[2] = (short)f2bf(v.z); o[3] = (short)f2bf(v.w);
    *(s4v*)(xu + (size_t)n * DDIM + d0) = o;
}

// ---------------- cast item_lin_w to bf16 in MFMA B-fragment order ----------
__global__ __launch_bounds__(256) void k_cast_w(const float* __restrict__ W,
                                                u16* __restrict__ wbf) {
    int idx = blockIdx.x * 256 + threadIdx.x;   // 2560 lane-slots
    if (idx >= 2560) return;
    int f = idx >> 6, lane = idx & 63;
    int q = lane >> 4, c = lane & 15;
    int kstep = f >> 2, nb = f & 3;
    u16* dst = wbf + (size_t)idx * 8;
#pragma unroll
    for (int j = 0; j < 8; j++) {
        int k = kstep * 32 + q * 8 + j;
        float v = (k < FDIM) ? W[k * DDIM + nb * 16 + c] : 0.f;
        dst[j] = f2bf(v);
    }
}

// ---------------- item linear via MFMA: xi = item_x @ W + b ------------------
__global__ __launch_bounds__(256) void k_item_lin2(const float* __restrict__ ix,
                                                   const u16* __restrict__ wbf,
                                                   const float* __restrict__ b,
                                                   u16* __restrict__ xi) {
    __shared__ __align__(16) u16 wl[40 * 64 * 8];   // 40960 B
    int tid = threadIdx.x;
    for (int i = tid; i < 2560; i += 256)
        ((f4v*)wl)[i] = ((const f4v*)wbf)[i];
    __syncthreads();

    int lane = tid & 63;
    int q = lane >> 4, c = lane & 15;
    float bv[4];
#pragma unroll
    for (int nb = 0; nb < 4; nb++) bv[nb] = b[nb * 16 + c];

    int w = blockIdx.x * 4 + (tid >> 6);
    int stride = gridDim.x * 4;
    const int NT = NIi / 16;   // 6250
    for (int t = w; t < NT; t += stride) {
        int row = t * 16 + c;
        const float* xr = ix + (size_t)row * FDIM;
        f4v acc[4];
#pragma unroll
        for (int nb = 0; nb < 4; nb++) {
            acc[nb][0] = bv[nb]; acc[nb][1] = bv[nb];
            acc[nb][2] = bv[nb]; acc[nb][3] = bv[nb];
        }
#pragma unroll
        for (int ks = 0; ks < 10; ks++) {
            s8v a;
            if (ks < 9 || q == 0) {
                float4 v0 = *(const float4*)(xr + ks * 32 + q * 8);
                float4 v1 = *(const float4*)(xr + ks * 32 + q * 8 + 4);
                a[0] = (short)f2bf(v0.x); a[1] = (short)f2bf(v0.y);
                a[2] = (short)f2bf(v0.z); a[3] = (short)f2bf(v0.w);
                a[4] = (short)f2bf(v1.x); a[5] = (short)f2bf(v1.y);
                a[6] = (short)f2bf(v1.z); a[7] = (short)f2bf(v1.w);
            } else {   // ks==9, q==1: k = 296..303, valid only 296..299
                float4 v0 = *(const float4*)(xr + 296);
                a[0] = (short)f2bf(v0.x); a[1] = (short)f2bf(v0.y);
                a[2] = (short)f2bf(v0.z); a[3] = (short)f2bf(v0.w);
                a[4] = 0; a[5] = 0; a[6] = 0; a[7] = 0;
            }
#pragma unroll
            for (int nb = 0; nb < 4; nb++) {
                s8v bb = *(const s8v*)(wl + ((size_t)(ks * 4 + nb) * 64 + lane) * 8);
                acc[nb] = __builtin_amdgcn_mfma_f32_16x16x32_bf16(a, bb, acc[nb], 0, 0, 0);
            }
        }
#pragma unroll
        for (int nb = 0; nb < 4; nb++)
#pragma unroll
            for (int r = 0; r < 4; r++)
                xi[(size_t)(t * 16 + q * 4 + r) * DDIM + nb * 16 + c] = f2bf(acc[nb][r]);
    }
}

// ---------------- bucket histogram (LDS-aggregated) --------------------------
__global__ __launch_bounds__(256) void k_hist(const int* __restrict__ src,
                                              const int* __restrict__ dst,
                                              int* __restrict__ hist) {
    __shared__ int h[NBT];
    int t = threadIdx.x;
    for (int c = t; c < NBT; c += 256) h[c] = 0;
    __syncthreads();
    int base = blockIdx.x * 2048;
#pragma unroll
    for (int k = 0; k < 8; k++) {
        int e = base + k * 256 + t;
        if (e < NEe) {
            int s = src[e], d = dst[e];
            atomicAdd(&h[d >> BSZL], 1);
            atomicAdd(&h[NB_I + (s >> BSZL)], 1);
        }
    }
    __syncthreads();
    for (int c = t; c < NBT; c += 256) {
        int n = h[c];
        if (n) atomicAdd(&hist[c], n);
    }
}

// ---------------- single-block exclusive scan (up to 4096 elems) -------------
__device__ __forceinline__ void scanN(const int* __restrict__ cnt, int n, int total,
                                      int* __restrict__ base, int* __restrict__ frontier,
                                      int* sb) {
    int t = threadIdx.x;
    int v[16]; int s = 0;
#pragma unroll
    for (int i = 0; i < 16; i++) {
        int idx = t * 16 + i;
        v[i] = (idx < n) ? cnt[idx] : 0;
        s += v[i];
    }
    sb[t] = s; __syncthreads();
    for (int o = 1; o < 256; o <<= 1) {
        int a = (t >= o) ? sb[t - o] : 0;
        __syncthreads();
        sb[t] += a;
        __syncthreads();
    }
    int run = sb[t] - s;
#pragma unroll
    for (int i = 0; i < 16; i++) {
        int idx = t * 16 + i;
        if (idx < n) { base[idx] = run; frontier[idx] = run; }
        run += v[i];
    }
    if (t == 0) base[n] = total;
    __syncthreads();
}

__global__ __launch_bounds__(256) void k_bucket_scan(const int* __restrict__ hist,
                                                     int* __restrict__ base_i, int* __restrict__ fr_i,
                                                     int* __restrict__ base_u, int* __restrict__ fr_u) {
    __shared__ int sb[256];
    scanN(hist, NB_I, NEe, base_i, fr_i, sb);
    scanN(hist + NB_I, NB_U, NEe, base_u, fr_u, sb);
}

// ---------------- scatter edges into bucket-ordered arrays -------------------
__global__ __launch_bounds__(256) void k_scatter(const int* __restrict__ src,
                                                 const int* __restrict__ dst,
                                                 int* __restrict__ fr_i, int* __restrict__ fr_u,
                                                 unsigned* __restrict__ scat_i,
                                                 unsigned* __restrict__ scat_u) {
    __shared__ int h[NBT];
    int t = threadIdx.x;
    for (int c = t; c < NBT; c += 256) h[c] = 0;
    __syncthreads();
    int base = blockIdx.x * 2048;
#pragma unroll
    for (int k = 0; k < 8; k++) {
        int e = base + k * 256 + t;
        if (e < NEe) {
            int s = src[e], d = dst[e];
            atomicAdd(&h[d >> BSZL], 1);
            atomicAdd(&h[NB_I + (s >> BSZL)], 1);
        }
    }
    __syncthreads();
    for (int c = t; c < NBT; c += 256) {
        int n = h[c];
        if (n) {
            int b = (c < NB_I) ? atomicAdd(&fr_i[c], n) : atomicAdd(&fr_u[c - NB_I], n);
            h[c] = b;
        }
    }
    __syncthreads();
#pragma unroll
    for (int k = 0; k < 8; k++) {
        int e = base + k * 256 + t;
        if (e < NEe) {
            int s = src[e], d = dst[e];
            int p = atomicAdd(&h[d >> BSZL], 1);
            scat_i[p] = (unsigned)s | ((unsigned)(d & (BSZ - 1)) << SH_I);
            int q = atomicAdd(&h[NB_I + (s >> BSZL)], 1);
            scat_u[q] = (unsigned)d | ((unsigned)(s & (BSZ - 1)) << SH_U);
        }
    }
}

// ---------------- push-based segment-mean: one block per 128-node bucket -----
// Edge-parallel: 8 lanes x 16 B per edge gather, fp32 accumulate in LDS via
// ds_add_f32 (stride-65 rows: bank = (row+ch)%32 -> <=2-way, free).
__global__ __launch_bounds__(256) void k_pagg(const u16* __restrict__ feat,
                                              u16* __restrict__ out,
                                              const unsigned* __restrict__ scat,
                                              const int* __restrict__ base,
                                              int shift, int ntotal) {
    __shared__ float accum[BSZ * ASTRIDE];   // 33280 B
    __shared__ int cnt_s[BSZ];
    int t = threadIdx.x;
    int b = blockIdx.x;
    int e0 = base[b], e1 = base[b + 1];
    int node0 = b << BSZL;
    unsigned mask = (1u << shift) - 1u;
    int c8 = t & 7;          // 16-B slice of the 128-B row
    int sub = t >> 3;        // edge sub-slot 0..31 within block

    for (int i = t; i < BSZ * ASTRIDE / 4; i += 256) ((f4v*)accum)[i] = f4v{0.f, 0.f, 0.f, 0.f};
    if (t < BSZ) cnt_s[t] = 0;
    __syncthreads();

    // main edge loop, unrolled x2 for memory-level parallelism
    int e = e0 + sub;
    for (; e + 32 < e1; e += 64) {
        unsigned vA = scat[e];
        unsigned vB = scat[e + 32];
        int sA = (int)(vA & mask), dA = (int)(vA >> shift);
        int sB = (int)(vB & mask), dB = (int)(vB >> shift);
        s8v rA = *(const s8v*)(feat + (size_t)sA * DDIM + c8 * 8);
        s8v rB = *(const s8v*)(feat + (size_t)sB * DDIM + c8 * 8);
        if (c8 == 0) { atomicAdd(&cnt_s[dA], 1); atomicAdd(&cnt_s[dB], 1); }
        float* pA = accum + dA * ASTRIDE + c8 * 8;
        float* pB = accum + dB * ASTRIDE + c8 * 8;
#pragma unroll
        for (int k = 0; k < 8; k++) atomicAdd(&pA[k], bf2f((u16)rA[k]));
#pragma unroll
        for (int k = 0; k < 8; k++) atomicAdd(&pB[k], bf2f((u16)rB[k]));
    }
    if (e < e1) {
        unsigned v = scat[e];
        int s = (int)(v & mask), d = (int)(v >> shift);
        s8v r = *(const s8v*)(feat + (size_t)s * DDIM + c8 * 8);
        if (c8 == 0) atomicAdd(&cnt_s[d], 1);
        float* p = accum + d * ASTRIDE + c8 * 8;
#pragma unroll
        for (int k = 0; k < 8; k++) atomicAdd(&p[k], bf2f((u16)r[k]));
    }
    __syncthreads();

    // writeout: 8 lanes per node, 16 B per lane
#pragma unroll
    for (int it = 0; it < 4; it++) {
        int r = it * 32 + sub;
        int node = node0 + r;
        if (node < ntotal) {
            int deg = cnt_s[r];
            float sc = deg > 0 ? 1.0f / (float)deg : 0.f;
            const float* ap = accum + r * ASTRIDE + c8 * 8;
            s8v o;
#pragma unroll
            for (int k = 0; k < 8; k++) o[k] = (short)f2bf(ap[k] * sc);
            *(s8v*)(out + (size_t)node * DDIM + c8 * 8) = o;
        }
    }
}

// ---------------- fused transform: out = [relu](agg@Wl + x@Wr + b), MFMA -----
__global__ __launch_bounds__(256) void k_transform(const u16* __restrict__ aggf,
                                                   const u16* __restrict__ xf,
                                                   const float* __restrict__ Wl,
                                                   const float* __restrict__ Wr,
                                                   const float* __restrict__ bias,
                                                   u16* __restrict__ out,
                                                   int ntiles, int relu) {
    int lane = threadIdx.x & 63;
    int q = lane >> 4, c = lane & 15;
    int w = blockIdx.x * 4 + (threadIdx.x >> 6);
    int stride = gridDim.x * 4;

    s8v wl[2][4], wrg[2][4];
#pragma unroll
    for (int ks = 0; ks < 2; ks++)
#pragma unroll
        for (int nb = 0; nb < 4; nb++) {
            s8v fl, fr;
#pragma unroll
            for (int j = 0; j < 8; j++) {
                int row = ks * 32 + q * 8 + j;
                int cc = nb * 16 + c;
                fl[j] = (short)f2bf(Wl[row * DDIM + cc]);
                fr[j] = (short)f2bf(Wr[row * DDIM + cc]);
            }
            wl[ks][nb] = fl; wrg[ks][nb] = fr;
        }
    float bv[4];
#pragma unroll
    for (int nb = 0; nb < 4; nb++) bv[nb] = bias[nb * 16 + c];

    for (int t = w; t < ntiles; t += stride) {
        const s8v* pa = (const s8v*)(aggf + (size_t)(t * 16 + c) * DDIM + q * 8);
        const s8v* px = (const s8v*)(xf   + (size_t)(t * 16 + c) * DDIM + q * 8);
        s8v a0 = pa[0], a1 = pa[4], x0 = px[0], x1 = px[4];
        f4v acc[4];
#pragma unroll
        for (int nb = 0; nb < 4; nb++) {
            acc[nb][0] = bv[nb]; acc[nb][1] = bv[nb];
            acc[nb][2] = bv[nb]; acc[nb][3] = bv[nb];
        }
#pragma unroll
        for (int nb = 0; nb < 4; nb++) {
            acc[nb] = __builtin_amdgcn_mfma_f32_16x16x32_bf16(a0, wl[0][nb],  acc[nb], 0, 0, 0);
            acc[nb] = __builtin_amdgcn_mfma_f32_16x16x32_bf16(a1, wl[1][nb],  acc[nb], 0, 0, 0);
            acc[nb] = __builtin_amdgcn_mfma_f32_16x16x32_bf16(x0, wrg[0][nb], acc[nb], 0, 0, 0);
            acc[nb] = __builtin_amdgcn_mfma_f32_16x16x32_bf16(x1, wrg[1][nb], acc[nb], 0, 0, 0);
        }
#pragma unroll
        for (int nb = 0; nb < 4; nb++)
#pragma unroll
            for (int r = 0; r < 4; r++) {
                float v = acc[nb][r];
                if (relu) v = fmaxf(v, 0.f);
                out[(size_t)(t * 16 + q * 4 + r) * DDIM + nb * 16 + c] = f2bf(v);
            }
    }
}

// ---------------- final dot predictor (8 edges per wave, 16 B/lane) ----------
__global__ __launch_bounds__(256) void k_dot(const u16* __restrict__ hu,
                                             const u16* __restrict__ hi,
                                             const int* __restrict__ ls,
                                             const int* __restrict__ ld,
                                             float* __restrict__ out) {
    int lane = threadIdx.x & 63;
    int sub = lane >> 3, t8 = lane & 7;
    int w = blockIdx.x * 4 + (threadIdx.x >> 6);
    int stride = gridDim.x * 4;
    const int ngroups = ELl / 8;
    for (int g = w; g < ngroups; g += stride) {
        int e = g * 8 + sub;
        int u = ls[e], it = ld[e];
        s8v av = *(const s8v*)(hu + (size_t)u  * DDIM + t8 * 8);
        s8v bv = *(const s8v*)(hi + (size_t)it * DDIM + t8 * 8);
        float s = 0.f;
#pragma unroll
        for (int k = 0; k < 8; k++) s += bf2f((u16)av[k]) * bf2f((u16)bv[k]);
        s += __shfl_xor(s, 4);
        s += __shfl_xor(s, 2);
        s += __shfl_xor(s, 1);
        if (t8 == 0) out[e] = s;
    }
}

extern "C" void kernel_launch(void* const* d_in, const int* in_sizes, int n_in,
                              void* d_out, int out_size, void* d_ws, size_t ws_size,
                              hipStream_t stream) {
    const float* user_emb = (const float*)d_in[0];
    const float* item_x   = (const float*)d_in[1];
    const float* item_w   = (const float*)d_in[2];
    const float* item_b   = (const float*)d_in[3];
    const float* Wl1_ui = (const float*)d_in[4];
    const float* Wr1_ui = (const float*)d_in[5];
    const float* b1_ui  = (const float*)d_in[6];
    const float* Wl1_iu = (const float*)d_in[7];
    const float* Wr1_iu = (const float*)d_in[8];
    const float* b1_iu  = (const float*)d_in[9];
    const float* Wl2_ui = (const float*)d_in[10];
    const float* Wr2_ui = (const float*)d_in[11];
    const float* b2_ui  = (const float*)d_in[12];
    const float* Wl2_iu = (const float*)d_in[13];
    const float* Wr2_iu = (const float*)d_in[14];
    const float* b2_iu  = (const float*)d_in[15];
    const int* uid  = (const int*)d_in[16];
    const int* esrc = (const int*)d_in[17];
    const int* edst = (const int*)d_in[18];
    const int* lsrc = (const int*)d_in[19];
    const int* ldst = (const int*)d_in[20];
    float* out = (float*)d_out;

    char* ws = (char*)d_ws;
    size_t off = 0;
    auto alloc = [&](size_t bytes) -> void* {
        void* p = ws + off;
        off += (bytes + 255) & ~(size_t)255;
        return p;
    };
    u16* xu_b   = (u16*)alloc((size_t)NUu * DDIM * 2);
    u16* hu1_b  = (u16*)alloc((size_t)NUu * DDIM * 2);
    u16* aggu_b = (u16*)alloc((size_t)NUu * DDIM * 2);   // also hu2
    u16* xi_b   = (u16*)alloc((size_t)NIi * DDIM * 2);
    u16* hi1_b  = (u16*)alloc((size_t)NIi * DDIM * 2);
    u16* aggi_b = (u16*)alloc((size_t)NIi * DDIM * 2);   // also hi2
    unsigned* scat_i = (unsigned*)alloc((size_t)NEe * 4);   // bucket-sorted edges (item side)
    unsigned* scat_u = (unsigned*)alloc((size_t)NEe * 4);   // bucket-sorted edges (user side)
    int* hist   = (int*)alloc((size_t)NBT * 4);
    int* base_i = (int*)alloc((size_t)(NB_I + 1) * 4);
    int* base_u = (int*)alloc((size_t)(NB_U + 1) * 4);
    int* fr_i   = (int*)alloc((size_t)NB_I * 4);
    int* fr_u   = (int*)alloc((size_t)NB_U * 4);
    u16* wbf    = (u16*)alloc((size_t)40 * 64 * 8 * 2);   // item W, frag order

    // ---- bucket-sort edges ----
    hipMemsetAsync(hist, 0, (size_t)NBT * 4, stream);
    int nchunks = (NEe + 2047) / 2048;   // 977
    k_hist<<<nchunks, 256, 0, stream>>>(esrc, edst, hist);
    k_bucket_scan<<<1, 256, 0, stream>>>(hist, base_i, fr_i, base_u, fr_u);
    k_scatter<<<nchunks, 256, 0, stream>>>(esrc, edst, fr_i, fr_u, scat_i, scat_u);

    // ---- input features ----
    k_cast_w<<<10, 256, 0, stream>>>(item_w, wbf);
    k_cast_users<<<NUu * 16 / 256, 256, 0, stream>>>(user_emb, uid, xu_b);
    k_item_lin2<<<512, 256, 0, stream>>>(item_x, wbf, item_b, xi_b);

    const int NT_I = NIi / 16;   // 6250
    const int NT_U = NUu / 16;   // 31250

    // layer 1
    k_pagg<<<NB_I, 256, 0, stream>>>(xu_b, aggi_b, scat_i, base_i, SH_I, NIi);
    k_transform<<<512, 256, 0, stream>>>(aggi_b, xi_b, Wl1_ui, Wr1_ui, b1_ui, hi1_b, NT_I, 1);
    k_pagg<<<NB_U, 256, 0, stream>>>(xi_b, aggu_b, scat_u, base_u, SH_U, NUu);
    k_transform<<<1024, 256, 0, stream>>>(aggu_b, xu_b, Wl1_iu, Wr1_iu, b1_iu, hu1_b, NT_U, 1);

    // layer 2 (hi2 aliases aggi_b, hu2 aliases aggu_b: per-tile read-before-write)
    k_pagg<<<NB_I, 256, 0, stream>>>(hu1_b, aggi_b, scat_i, base_i, SH_I, NIi);
    k_transform<<<512, 256, 0, stream>>>(aggi_b, hi1_b, Wl2_ui, Wr2_ui, b2_ui, aggi_b, NT_I, 0);
    k_pagg<<<NB_U, 256, 0, stream>>>(hi1_b, aggu_b, scat_u, base_u, SH_U, NUu);
    k_transform<<<1024, 256, 0, stream>>>(aggu_b, hu1_b, Wl2_iu, Wr2_iu, b2_iu, aggu_b, NT_U, 0);

    // predictor
    k_dot<<<2048, 256, 0, stream>>>(aggu_b, aggi_b, lsrc, ldst, out);
}

// Round 5
// 911.384 us; speedup vs baseline: 3.9837x; 3.9837x over previous
//
#include <hip/hip_runtime.h>

#define NUu 500000
#define NIi 100000
#define FDIM 300
#define DDIM 64
#define NEe 2000000
#define ELl 1000000

// bucket config for CSR build (round-2 verified)
#define BSZL_I 8      // 256 items per bucket
#define BSZL_U 9      // 512 users per bucket
#define NB_I 391      // ceil(NIi/256)
#define NB_U 977      // ceil(NUu/512)
#define NBT (NB_I + NB_U)   // 1368
#define SH_I 19       // src < 2^19 packed low, d_local<<19
#define SH_U 17       // dst < 2^17 packed low, s_local<<17

typedef __attribute__((ext_vector_type(8))) short s8v;
typedef __attribute__((ext_vector_type(4))) short s4v;
typedef __attribute__((ext_vector_type(4))) float f4v;
typedef unsigned short u16;

__device__ __forceinline__ float bf2f(u16 h) {
    union { unsigned u; float f; } x; x.u = ((unsigned)h) << 16; return x.f;
}
__device__ __forceinline__ u16 f2bf(float f) {
    union { float f; unsigned u; } x; x.f = f;
    unsigned u = x.u;
    u += 0x7FFFu + ((u >> 16) & 1u);   // round-to-nearest-even
    return (u16)(u >> 16);
}

// ---------------- cast user embeddings (with user_node_id gather) to bf16 ----
__global__ __launch_bounds__(256) void k_cast_users(const float* __restrict__ ue,
                                                    const int* __restrict__ uid,
                                                    u16* __restrict__ xu) {
    int idx = blockIdx.x * 256 + threadIdx.x;   // one thread = 4 elems
    int n  = idx >> 4;
    int d0 = (idx & 15) * 4;
    int src = uid[n];
    const float4* p = (const float4*)(ue + (size_t)src * DDIM + d0);
    float4 v = *p;
    s4v o;
    o[0] = (short)f2bf(v.x); o[1] = (short)f2bf(v.y);
    o[2] = (short)f2bf(v.z); o[3] = (short)f2bf(v.w);
    *(s4v*)(xu + (size_t)n * DDIM + d0) = o;
}

// ---------------- cast item_lin_w to bf16 in MFMA B-fragment order ----------
__global__ __launch_bounds__(256) void k_cast_w(const float* __restrict__ W,
                                                u16* __restrict__ wbf) {
    int idx = blockIdx.x * 256 + threadIdx.x;   // 2560 lane-slots
    if (idx >= 2560) return;
    int f = idx >> 6, lane = idx & 63;
    int q = lane >> 4, c = lane & 15;
    int kstep = f >> 2, nb = f & 3;
    u16* dst = wbf + (size_t)idx * 8;
#pragma unroll
    for (int j = 0; j < 8; j++) {
        int k = kstep * 32 + q * 8 + j;
        float v = (k < FDIM) ? W[k * DDIM + nb * 16 + c] : 0.f;
        dst[j] = f2bf(v);
    }
}

// ---------------- item linear via MFMA: xi = item_x @ W + b ------------------
__global__ __launch_bounds__(256) void k_item_lin2(const float* __restrict__ ix,
                                                   const u16* __restrict__ wbf,
                                                   const float* __restrict__ b,
                                                   u16* __restrict__ xi) {
    __shared__ __align__(16) u16 wl[40 * 64 * 8];   // 40960 B
    int tid = threadIdx.x;
    for (int i = tid; i < 2560; i += 256)
        ((f4v*)wl)[i] = ((const f4v*)wbf)[i];
    __syncthreads();

    int lane = tid & 63;
    int q = lane >> 4, c = lane & 15;
    float bv[4];
#pragma unroll
    for (int nb = 0; nb < 4; nb++) bv[nb] = b[nb * 16 + c];

    int w = blockIdx.x * 4 + (tid >> 6);
    int stride = gridDim.x * 4;
    const int NT = NIi / 16;   // 6250
    for (int t = w; t < NT; t += stride) {
        int row = t * 16 + c;
        const float* xr = ix + (size_t)row * FDIM;
        f4v acc[4];
#pragma unroll
        for (int nb = 0; nb < 4; nb++) {
            acc[nb][0] = bv[nb]; acc[nb][1] = bv[nb];
            acc[nb][2] = bv[nb]; acc[nb][3] = bv[nb];
        }
#pragma unroll
        for (int ks = 0; ks < 10; ks++) {
            s8v a;
            if (ks < 9 || q == 0) {
                float4 v0 = *(const float4*)(xr + ks * 32 + q * 8);
                float4 v1 = *(const float4*)(xr + ks * 32 + q * 8 + 4);
                a[0] = (short)f2bf(v0.x); a[1] = (short)f2bf(v0.y);
                a[2] = (short)f2bf(v0.z); a[3] = (short)f2bf(v0.w);
                a[4] = (short)f2bf(v1.x); a[5] = (short)f2bf(v1.y);
                a[6] = (short)f2bf(v1.z); a[7] = (short)f2bf(v1.w);
            } else {   // ks==9, q==1: k = 296..303, valid only 296..299
                float4 v0 = *(const float4*)(xr + 296);
                a[0] = (short)f2bf(v0.x); a[1] = (short)f2bf(v0.y);
                a[2] = (short)f2bf(v0.z); a[3] = (short)f2bf(v0.w);
                a[4] = 0; a[5] = 0; a[6] = 0; a[7] = 0;
            }
#pragma unroll
            for (int nb = 0; nb < 4; nb++) {
                s8v bb = *(const s8v*)(wl + ((size_t)(ks * 4 + nb) * 64 + lane) * 8);
                acc[nb] = __builtin_amdgcn_mfma_f32_16x16x32_bf16(a, bb, acc[nb], 0, 0, 0);
            }
        }
#pragma unroll
        for (int nb = 0; nb < 4; nb++)
#pragma unroll
            for (int r = 0; r < 4; r++)
                xi[(size_t)(t * 16 + q * 4 + r) * DDIM + nb * 16 + c] = f2bf(acc[nb][r]);
    }
}

// ---------------- CSR build: bucketed multisplit (round-2 verified) ----------
__global__ __launch_bounds__(256) void k_hist(const int* __restrict__ src,
                                              const int* __restrict__ dst,
                                              int* __restrict__ hist) {
    __shared__ int h[NBT];
    int t = threadIdx.x;
    for (int c = t; c < NBT; c += 256) h[c] = 0;
    __syncthreads();
    int base = blockIdx.x * 2048;
#pragma unroll
    for (int k = 0; k < 8; k++) {
        int e = base + k * 256 + t;
        if (e < NEe) {
            int s = src[e], d = dst[e];
            atomicAdd(&h[d >> BSZL_I], 1);
            atomicAdd(&h[NB_I + (s >> BSZL_U)], 1);
        }
    }
    __syncthreads();
    for (int c = t; c < NBT; c += 256) {
        int n = h[c];
        if (n) atomicAdd(&hist[c], n);
    }
}

__device__ __forceinline__ void scanN(const int* __restrict__ cnt, int n, int total,
                                      int* __restrict__ base, int* __restrict__ frontier,
                                      int* sb) {
    int t = threadIdx.x;
    int v[8]; int s = 0;
#pragma unroll
    for (int i = 0; i < 8; i++) {
        int idx = t * 8 + i;
        v[i] = (idx < n) ? cnt[idx] : 0;
        s += v[i];
    }
    sb[t] = s; __syncthreads();
    for (int o = 1; o < 256; o <<= 1) {
        int a = (t >= o) ? sb[t - o] : 0;
        __syncthreads();
        sb[t] += a;
        __syncthreads();
    }
    int run = sb[t] - s;
#pragma unroll
    for (int i = 0; i < 8; i++) {
        int idx = t * 8 + i;
        if (idx < n) { base[idx] = run; frontier[idx] = run; }
        run += v[i];
    }
    if (t == 0) base[n] = total;
    __syncthreads();
}

__global__ __launch_bounds__(256) void k_bucket_scan(const int* __restrict__ hist,
                                                     int* __restrict__ base_i, int* __restrict__ fr_i,
                                                     int* __restrict__ base_u, int* __restrict__ fr_u,
                                                     int* __restrict__ rpi, int* __restrict__ rpu) {
    __shared__ int sb[256];
    scanN(hist, NB_I, NEe, base_i, fr_i, sb);
    scanN(hist + NB_I, NB_U, NEe, base_u, fr_u, sb);
    if (threadIdx.x == 0) { rpi[NIi] = NEe; rpu[NUu] = NEe; }
}

__global__ __launch_bounds__(256) void k_scatter(const int* __restrict__ src,
                                                 const int* __restrict__ dst,
                                                 int* __restrict__ fr_i, int* __restrict__ fr_u,
                                                 unsigned* __restrict__ scat_i,
                                                 unsigned* __restrict__ scat_u) {
    __shared__ int h[NBT];
    int t = threadIdx.x;
    for (int c = t; c < NBT; c += 256) h[c] = 0;
    __syncthreads();
    int base = blockIdx.x * 2048;
#pragma unroll
    for (int k = 0; k < 8; k++) {
        int e = base + k * 256 + t;
        if (e < NEe) {
            int s = src[e], d = dst[e];
            atomicAdd(&h[d >> BSZL_I], 1);
            atomicAdd(&h[NB_I + (s >> BSZL_U)], 1);
        }
    }
    __syncthreads();
    for (int c = t; c < NBT; c += 256) {
        int n = h[c];
        if (n) {
            int b = (c < NB_I) ? atomicAdd(&fr_i[c], n) : atomicAdd(&fr_u[c - NB_I], n);
            h[c] = b;
        }
    }
    __syncthreads();
#pragma unroll
    for (int k = 0; k < 8; k++) {
        int e = base + k * 256 + t;
        if (e < NEe) {
            int s = src[e], d = dst[e];
            int p = atomicAdd(&h[d >> BSZL_I], 1);
            scat_i[p] = (unsigned)s | ((unsigned)(d & 255) << SH_I);
            int q = atomicAdd(&h[NB_I + (s >> BSZL_U)], 1);
            scat_u[q] = (unsigned)d | ((unsigned)(s & 511) << SH_U);
        }
    }
}

__global__ __launch_bounds__(256) void k_bfill(const unsigned* __restrict__ scat,
                                               const int* __restrict__ base,
                                               int* __restrict__ rp, int* __restrict__ col,
                                               int shift, int bszlog, int ntotal) {
    __shared__ int cnt[512];
    __shared__ int pos[512];
    __shared__ int sb[256];
    int b = blockIdx.x;
    int t = threadIdx.x;
    int e0 = base[b], e1 = base[b + 1];
    int node0 = b << bszlog;
    int bsz = 1 << bszlog;
    unsigned mask = (1u << shift) - 1u;

    for (int c = t; c < bsz; c += 256) cnt[c] = 0;
    __syncthreads();
    for (int e = e0 + t; e < e1; e += 256) {
        unsigned v = scat[e];
        atomicAdd(&cnt[v >> shift], 1);
    }
    __syncthreads();
    int per = bsz >> 8;
    int loc[2]; int ls = 0;
#pragma unroll
    for (int i = 0; i < 2; i++) {
        loc[i] = (i < per) ? cnt[t * per + i] : 0;
        ls += loc[i];
    }
    sb[t] = ls; __syncthreads();
    for (int o = 1; o < 256; o <<= 1) {
        int a = (t >= o) ? sb[t - o] : 0;
        __syncthreads();
        sb[t] += a;
        __syncthreads();
    }
    int run = e0 + sb[t] - ls;
#pragma unroll
    for (int i = 0; i < 2; i++) {
        if (i < per) {
            int idx = t * per + i;
            int node = node0 + idx;
            if (node < ntotal) rp[node] = run;
            pos[idx] = run;
            run += loc[i];
        }
    }
    __syncthreads();
    for (int e = e0 + t; e < e1; e += 256) {
        unsigned v = scat[e];
        int l = v >> shift;
        int p = atomicAdd(&pos[l], 1);
        col[p] = (int)(v & mask);
    }
}

// ---------------- fused agg-mean + transform: out = [relu](mean@Wl + x@Wr + b)
// One wave per 16-node tile. Lane (q,c): node c, channels {q*8..q*8+7} and
// {32+q*8..}. Per-lane private neighbor loop -> 16 independent gather chains
// per wave; fp32 register accumulate; no shfl; A-fragments built in place.
__global__ __launch_bounds__(256) void k_aggform(const u16* __restrict__ gfeat,
                                                 const u16* __restrict__ xf,
                                                 const float* __restrict__ Wl,
                                                 const float* __restrict__ Wr,
                                                 const float* __restrict__ bias,
                                                 u16* __restrict__ out,
                                                 const int* __restrict__ rp,
                                                 const int* __restrict__ col,
                                                 int ntiles, int relu) {
    int lane = threadIdx.x & 63;
    int q = lane >> 4, c = lane & 15;
    int w = blockIdx.x * 4 + (threadIdx.x >> 6);
    int stride = gridDim.x * 4;

    s8v wl[2][4], wrg[2][4];
#pragma unroll
    for (int ks = 0; ks < 2; ks++)
#pragma unroll
        for (int nb = 0; nb < 4; nb++) {
            s8v fl, fr;
#pragma unroll
            for (int j = 0; j < 8; j++) {
                int row = ks * 32 + q * 8 + j;
                int cc = nb * 16 + c;
                fl[j] = (short)f2bf(Wl[row * DDIM + cc]);
                fr[j] = (short)f2bf(Wr[row * DDIM + cc]);
            }
            wl[ks][nb] = fl; wrg[ks][nb] = fr;
        }
    float bv[4];
#pragma unroll
    for (int nb = 0; nb < 4; nb++) bv[nb] = bias[nb * 16 + c];

    for (int t = w; t < ntiles; t += stride) {
        int node = t * 16 + c;
        int s0 = rp[node], s1 = rp[node + 1];
        float ag[16];
#pragma unroll
        for (int k = 0; k < 16; k++) ag[k] = 0.f;
        for (int j = s0; j < s1; j++) {
            int r = col[j];
            const u16* row = gfeat + (size_t)r * DDIM + q * 8;
            s8v lo = *(const s8v*)(row);
            s8v hi = *(const s8v*)(row + 32);
#pragma unroll
            for (int k = 0; k < 8; k++) {
                ag[k]     += bf2f((u16)lo[k]);
                ag[8 + k] += bf2f((u16)hi[k]);
            }
        }
        int deg = s1 - s0;
        float sc = deg > 0 ? 1.0f / (float)deg : 0.f;
        s8v a0, a1;
#pragma unroll
        for (int k = 0; k < 8; k++) {
            a0[k] = (short)f2bf(ag[k] * sc);
            a1[k] = (short)f2bf(ag[8 + k] * sc);
        }
        const s8v* px = (const s8v*)(xf + (size_t)node * DDIM + q * 8);
        s8v x0 = px[0], x1 = px[4];

        f4v acc[4];
#pragma unroll
        for (int nb = 0; nb < 4; nb++) {
            acc[nb][0] = bv[nb]; acc[nb][1] = bv[nb];
            acc[nb][2] = bv[nb]; acc[nb][3] = bv[nb];
        }
#pragma unroll
        for (int nb = 0; nb < 4; nb++) {
            acc[nb] = __builtin_amdgcn_mfma_f32_16x16x32_bf16(a0, wl[0][nb],  acc[nb], 0, 0, 0);
            acc[nb] = __builtin_amdgcn_mfma_f32_16x16x32_bf16(a1, wl[1][nb],  acc[nb], 0, 0, 0);
            acc[nb] = __builtin_amdgcn_mfma_f32_16x16x32_bf16(x0, wrg[0][nb], acc[nb], 0, 0, 0);
            acc[nb] = __builtin_amdgcn_mfma_f32_16x16x32_bf16(x1, wrg[1][nb], acc[nb], 0, 0, 0);
        }
#pragma unroll
        for (int nb = 0; nb < 4; nb++)
#pragma unroll
            for (int r = 0; r < 4; r++) {
                float v = acc[nb][r];
                if (relu) v = fmaxf(v, 0.f);
                out[(size_t)(t * 16 + q * 4 + r) * DDIM + nb * 16 + c] = f2bf(v);
            }
    }
}

// ---------------- final dot predictor (8 edges per wave, 16 B/lane) ----------
__global__ __launch_bounds__(256) void k_dot(const u16* __restrict__ hu,
                                             const u16* __restrict__ hi,
                                             const int* __restrict__ ls,
                                             const int* __restrict__ ld,
                                             float* __restrict__ out) {
    int lane = threadIdx.x & 63;
    int sub = lane >> 3, t8 = lane & 7;
    int w = blockIdx.x * 4 + (threadIdx.x >> 6);
    int stride = gridDim.x * 4;
    const int ngroups = ELl / 8;
    for (int g = w; g < ngroups; g += stride) {
        int e = g * 8 + sub;
        int u = ls[e], it = ld[e];
        s8v av = *(const s8v*)(hu + (size_t)u  * DDIM + t8 * 8);
        s8v bv = *(const s8v*)(hi + (size_t)it * DDIM + t8 * 8);
        float s = 0.f;
#pragma unroll
        for (int k = 0; k < 8; k++) s += bf2f((u16)av[k]) * bf2f((u16)bv[k]);
        s += __shfl_xor(s, 4);
        s += __shfl_xor(s, 2);
        s += __shfl_xor(s, 1);
        if (t8 == 0) out[e] = s;
    }
}

extern "C" void kernel_launch(void* const* d_in, const int* in_sizes, int n_in,
                              void* d_out, int out_size, void* d_ws, size_t ws_size,
                              hipStream_t stream) {
    const float* user_emb = (const float*)d_in[0];
    const float* item_x   = (const float*)d_in[1];
    const float* item_w   = (const float*)d_in[2];
    const float* item_b   = (const float*)d_in[3];
    const float* Wl1_ui = (const float*)d_in[4];
    const float* Wr1_ui = (const float*)d_in[5];
    const float* b1_ui  = (const float*)d_in[6];
    const float* Wl1_iu = (const float*)d_in[7];
    const float* Wr1_iu = (const float*)d_in[8];
    const float* b1_iu  = (const float*)d_in[9];
    const float* Wl2_ui = (const float*)d_in[10];
    const float* Wr2_ui = (const float*)d_in[11];
    const float* b2_ui  = (const float*)d_in[12];
    const float* Wl2_iu = (const float*)d_in[13];
    const float* Wr2_iu = (const float*)d_in[14];
    const float* b2_iu  = (const float*)d_in[15];
    const int* uid  = (const int*)d_in[16];
    const int* esrc = (const int*)d_in[17];
    const int* edst = (const int*)d_in[18];
    const int* lsrc = (const int*)d_in[19];
    const int* ldst = (const int*)d_in[20];
    float* out = (float*)d_out;

    char* ws = (char*)d_ws;
    size_t off = 0;
    auto alloc = [&](size_t bytes) -> void* {
        void* p = ws + off;
        off += (bytes + 255) & ~(size_t)255;
        return p;
    };
    u16* xu_b  = (u16*)alloc((size_t)NUu * DDIM * 2);
    u16* hu1_b = (u16*)alloc((size_t)NUu * DDIM * 2);
    u16* hu2_b = (u16*)alloc((size_t)NUu * DDIM * 2);
    u16* xi_b  = (u16*)alloc((size_t)NIi * DDIM * 2);
    u16* hi1_b = (u16*)alloc((size_t)NIi * DDIM * 2);
    u16* hi2_b = (u16*)alloc((size_t)NIi * DDIM * 2);
    int* coli = (int*)alloc((size_t)NEe * 4);
    int* colu = (int*)alloc((size_t)NEe * 4);
    int* rpi  = (int*)alloc((size_t)(NIi + 1) * 4);
    int* rpu  = (int*)alloc((size_t)(NUu + 1) * 4);
    int* hist   = (int*)alloc((size_t)NBT * 4);
    int* base_i = (int*)alloc((size_t)(NB_I + 1) * 4);
    int* base_u = (int*)alloc((size_t)(NB_U + 1) * 4);
    int* fr_i   = (int*)alloc((size_t)NB_I * 4);
    int* fr_u   = (int*)alloc((size_t)NB_U * 4);
    u16* wbf    = (u16*)alloc((size_t)40 * 64 * 8 * 2);   // item W, frag order
    // scatter staging aliases xu_b (16 MB < 64 MB): CSR build before k_cast_users
    unsigned* scat_i = (unsigned*)xu_b;
    unsigned* scat_u = (unsigned*)((char*)xu_b + (size_t)NEe * 4);

    // ---- CSR build (bucketed) ----
    hipMemsetAsync(hist, 0, (size_t)NBT * 4, stream);
    int nchunks = (NEe + 2047) / 2048;   // 977
    k_hist<<<nchunks, 256, 0, stream>>>(esrc, edst, hist);
    k_bucket_scan<<<1, 256, 0, stream>>>(hist, base_i, fr_i, base_u, fr_u, rpi, rpu);
    k_scatter<<<nchunks, 256, 0, stream>>>(esrc, edst, fr_i, fr_u, scat_i, scat_u);
    k_bfill<<<NB_I, 256, 0, stream>>>(scat_i, base_i, rpi, coli, SH_I, BSZL_I, NIi);
    k_bfill<<<NB_U, 256, 0, stream>>>(scat_u, base_u, rpu, colu, SH_U, BSZL_U, NUu);

    // ---- input features (after CSR build: scat_* alias xu_b) ----
    k_cast_w<<<10, 256, 0, stream>>>(item_w, wbf);
    k_cast_users<<<NUu * 16 / 256, 256, 0, stream>>>(user_emb, uid, xu_b);
    k_item_lin2<<<512, 256, 0, stream>>>(item_x, wbf, item_b, xi_b);

    const int NT_I = NIi / 16;   // 6250
    const int NT_U = NUu / 16;   // 31250

    // layer 1 (fused agg+transform)
    k_aggform<<<512, 256, 0, stream>>>(xu_b, xi_b, Wl1_ui, Wr1_ui, b1_ui, hi1_b,
                                       rpi, coli, NT_I, 1);
    k_aggform<<<2048, 256, 0, stream>>>(xi_b, xu_b, Wl1_iu, Wr1_iu, b1_iu, hu1_b,
                                        rpu, colu, NT_U, 1);
    // layer 2
    k_aggform<<<512, 256, 0, stream>>>(hu1_b, hi1_b, Wl2_ui, Wr2_ui, b2_ui, hi2_b,
                                       rpi, coli, NT_I, 0);
    k_aggform<<<2048, 256, 0, stream>>>(hi1_b, hu1_b, Wl2_iu, Wr2_iu, b2_iu, hu2_b,
                                        rpu, colu, NT_U, 0);

    // predictor
    k_dot<<<2048, 256, 0, stream>>>(hu2_b, hi2_b, lsrc, ldst, out);
}